// Round 7
// baseline (912.912 us; speedup 1.0000x reference)
//
#include <hip/hip_runtime.h>

#define IN_F 4096
#define OUT_F 11008

typedef __attribute__((ext_vector_type(8))) short bf16x8;   // 8 bf16 (4 VGPR) MFMA operand
typedef __attribute__((ext_vector_type(4))) float f32x4;
typedef __attribute__((ext_vector_type(4))) unsigned short us4;
typedef __attribute__((ext_vector_type(8))) unsigned short us8;

__device__ __forceinline__ unsigned short f2bf(float f) {
  unsigned int u = __float_as_uint(f);
  u += 0x7FFFu + ((u >> 16) & 1u);   // RNE
  return (unsigned short)(u >> 16);
}

// ---------------- prepass 1: X fp32 -> bf16 ----------------
__global__ __launch_bounds__(256) void cvt_x(const float* __restrict__ X,
                                             unsigned short* __restrict__ Xb, int n8) {
  for (int i = blockIdx.x * blockDim.x + threadIdx.x; i < n8;
       i += gridDim.x * blockDim.x) {
    const float4 a = reinterpret_cast<const float4*>(X)[2 * i];
    const float4 b = reinterpret_cast<const float4*>(X)[2 * i + 1];
    us8 h;
    h[0] = f2bf(a.x); h[1] = f2bf(a.y); h[2] = f2bf(a.z); h[3] = f2bf(a.w);
    h[4] = f2bf(b.x); h[5] = f2bf(b.y); h[6] = f2bf(b.z); h[7] = f2bf(b.w);
    reinterpret_cast<us8*>(Xb)[i] = h;
  }
}

// ---------------- prepass 2: W nf4 packed -> bf16 (dequant once) ----------------
__global__ __launch_bounds__(256) void dequant_w(const int* __restrict__ Wp,
                                                 const float* __restrict__ Amax,
                                                 unsigned short* __restrict__ Wb, int n4) {
  __shared__ float lutS[16];
  if (threadIdx.x < 16) {
    const float lut[16] = {-1.0f, -0.6961928009986877f, -0.5250730514526367f,
        -0.39491719007492065f, -0.28444138169288635f, -0.18477343022823334f,
        -0.08820830285549164f, 0.0f, 0.07107656449079514f, 0.14263366162776947f,
        0.22430233657360077f, 0.3203405737876892f, 0.4407068192958832f,
        0.5905631184577942f, 0.796090841293335f, 1.0f};
    lutS[threadIdx.x] = lut[threadIdx.x];
  }
  __syncthreads();
  for (int i = blockIdx.x * blockDim.x + threadIdx.x; i < n4;
       i += gridDim.x * blockDim.x) {
    const int j = i * 4;
    const int row = j >> 11;
    const int coli = j & 2047;
    const float am = Amax[row * (IN_F / 64) + (coli >> 5)];
    const int4 pk = reinterpret_cast<const int4*>(Wp)[i];
    us8 h; int c;
    c = pk.x & 255; h[0] = f2bf(lutS[c & 15] * am); h[1] = f2bf(lutS[c >> 4] * am);
    c = pk.y & 255; h[2] = f2bf(lutS[c & 15] * am); h[3] = f2bf(lutS[c >> 4] * am);
    c = pk.z & 255; h[4] = f2bf(lutS[c & 15] * am); h[5] = f2bf(lutS[c >> 4] * am);
    c = pk.w & 255; h[6] = f2bf(lutS[c & 15] * am); h[7] = f2bf(lutS[c >> 4] * am);
    reinterpret_cast<us8*>(Wb)[i] = h;
  }
}

// ---------------- main GEMM: 256x256, BK=64, dbuf-2, 4 phases/K-tile ----------------
#define MF(a, b, c) __builtin_amdgcn_mfma_f32_16x16x32_bf16(a, b, c, 0, 0, 0)
#define GLDS(src, dst) __builtin_amdgcn_global_load_lds( \
    (const __attribute__((address_space(1))) void*)(src), \
    (__attribute__((address_space(3))) void*)(dst), 16, 0, 0)
#define FENCE asm volatile("" ::: "memory")
#define BAR do { FENCE; __builtin_amdgcn_s_barrier(); FENCE; } while (0)
#define VM6 asm volatile("s_waitcnt vmcnt(6)" ::: "memory")
#define VM0 asm volatile("s_waitcnt vmcnt(0)" ::: "memory")
#define VMNOP do {} while (0)
#define P1 __builtin_amdgcn_s_setprio(1)
#define P0 __builtin_amdgcn_s_setprio(0)

__global__ __launch_bounds__(512, 2) void gemm256(
    const unsigned short* __restrict__ A,   // (M, K) bf16
    const unsigned short* __restrict__ B,   // (N, K) bf16
    const float* __restrict__ Bias, float* __restrict__ Out, int M) {
  extern __shared__ unsigned short sm[];    // 128 KiB = 2 bufs x {A kh0,A kh1,B kh0,B kh1} x 16 KiB
  char* const smc = (char*)sm;

  const int tid = threadIdx.x;
  const int l = tid & 63;
  const int wid = tid >> 6;

  const int Mb = M / 256;                   // 32
  const int Nb = OUT_F / 256;               // 43
  const int cpx = (Mb * Nb) >> 3;           // 172
  const int bid = (blockIdx.x & 7) * cpx + (blockIdx.x >> 3);
  const int m0 = (bid % Mb) * 256;          // m-fast: B-panel L2-resident per XCD
  const int n0 = (bid / Mb) * 256;

  // ---- read-side lane constant: logical (r,c) at chunk r*4 + (c ^ ((r>>2)&3)) ----
  const int lv = (l & 15) * 64 + (((l >> 4) ^ ((l >> 2) & 3)) * 16);   // bytes
  const int aLane = (wid >> 2) * 8192 + lv;            // + m*1024 per A frag
  const int bLane = 32768 + (wid & 3) * 4096 + lv;     // + (nh*2+j)*1024 per B frag

  // ---- stage-side lane constants (inverse-swizzled global source, linear LDS dest) ----
  const int rq = tid >> 2;                                   // row within 128-row half
  const int cs = (tid & 3) ^ ((tid >> 4) & 3);               // content k-chunk
  const unsigned short* gAs = A + (size_t)(m0 + rq) * IN_F + cs * 8;
  const unsigned short* gBs = B + (size_t)(n0 + rq) * IN_F + cs * 8;

  // unit = 16 KiB (256 rows x 32 k): 2 x global_load_lds per thread (i = 0,1 -> +128 rows)
#define SA(t, kh) do { \
    unsigned short* d_ = sm + (size_t)((((t) & 1) * 4096) + (kh) * 1024 + wid * 64) * 8; \
    const unsigned short* s_ = gAs + (size_t)(t) * 64 + (kh) * 32; \
    GLDS(s_, d_); GLDS(s_ + 524288, d_ + 4096); } while (0)
#define SB(t, kh) do { \
    unsigned short* d_ = sm + (size_t)((((t) & 1) * 4096) + 2048 + (kh) * 1024 + wid * 64) * 8; \
    const unsigned short* s_ = gBs + (size_t)(t) * 64 + (kh) * 32; \
    GLDS(s_, d_); GLDS(s_ + 524288, d_ + 4096); } while (0)

#define RD_A(kh) do { const char* p_ = LAb + (kh) * 16384; \
    a0 = *(const bf16x8*)(p_);        a1 = *(const bf16x8*)(p_ + 1024); \
    a2 = *(const bf16x8*)(p_ + 2048); a3 = *(const bf16x8*)(p_ + 3072); \
    a4 = *(const bf16x8*)(p_ + 4096); a5 = *(const bf16x8*)(p_ + 5120); \
    a6 = *(const bf16x8*)(p_ + 6144); a7 = *(const bf16x8*)(p_ + 7168); } while (0)
#define RD_B01(kh) do { const char* p_ = LBb + (kh) * 16384; \
    b0 = *(const bf16x8*)(p_); b1 = *(const bf16x8*)(p_ + 1024); } while (0)
#define RD_B23(kh) do { const char* p_ = LBb + (kh) * 16384 + 2048; \
    b2 = *(const bf16x8*)(p_); b3 = *(const bf16x8*)(p_ + 1024); } while (0)

#define MM16_01(B0, B1) do { \
    acc[0][0]=MF(a0,B0,acc[0][0]); acc[0][1]=MF(a0,B1,acc[0][1]); \
    acc[1][0]=MF(a1,B0,acc[1][0]); acc[1][1]=MF(a1,B1,acc[1][1]); \
    acc[2][0]=MF(a2,B0,acc[2][0]); acc[2][1]=MF(a2,B1,acc[2][1]); \
    acc[3][0]=MF(a3,B0,acc[3][0]); acc[3][1]=MF(a3,B1,acc[3][1]); \
    acc[4][0]=MF(a4,B0,acc[4][0]); acc[4][1]=MF(a4,B1,acc[4][1]); \
    acc[5][0]=MF(a5,B0,acc[5][0]); acc[5][1]=MF(a5,B1,acc[5][1]); \
    acc[6][0]=MF(a6,B0,acc[6][0]); acc[6][1]=MF(a6,B1,acc[6][1]); \
    acc[7][0]=MF(a7,B0,acc[7][0]); acc[7][1]=MF(a7,B1,acc[7][1]); } while (0)
#define MM16_23(B2, B3) do { \
    acc[0][2]=MF(a0,B2,acc[0][2]); acc[0][3]=MF(a0,B3,acc[0][3]); \
    acc[1][2]=MF(a1,B2,acc[1][2]); acc[1][3]=MF(a1,B3,acc[1][3]); \
    acc[2][2]=MF(a2,B2,acc[2][2]); acc[2][3]=MF(a2,B3,acc[2][3]); \
    acc[3][2]=MF(a3,B2,acc[3][2]); acc[3][3]=MF(a3,B3,acc[3][3]); \
    acc[4][2]=MF(a4,B2,acc[4][2]); acc[4][3]=MF(a4,B3,acc[4][3]); \
    acc[5][2]=MF(a5,B2,acc[5][2]); acc[5][3]=MF(a5,B3,acc[5][3]); \
    acc[6][2]=MF(a6,B2,acc[6][2]); acc[6][3]=MF(a6,B3,acc[6][3]); \
    acc[7][2]=MF(a7,B2,acc[7][2]); acc[7][3]=MF(a7,B3,acc[7][3]); } while (0)

  // KTILE(T): 4 phases; stage cadence p0:u(T+1,3) p1:u(T+2,0) p2:u(T+2,1) p3:u(T+2,2);
  // single VM6 at p3 (pre-BAR; next tile's reads post-BAR => all waves' loads landed).
  // WAR: each unit staged in the phase AFTER its region's last read (barrier-ordered).
#define KTILE(T, S1, S2, VMW) do { \
    const char* LAb = smc + (((T) & 1) << 16) + aLane; \
    const char* LBb = smc + (((T) & 1) << 16) + bLane; \
    bf16x8 a0, a1, a2, a3, a4, a5, a6, a7, b0, b1, b2, b3; \
    RD_A(0); RD_B01(0); \
    if (S1) SB((T) + 1, 1); \
    BAR; P1; MM16_01(b0, b1); P0; BAR; \
    RD_B23(0); \
    if (S2) SA((T) + 2, 0); \
    BAR; P1; MM16_23(b2, b3); P0; BAR; \
    RD_A(1); RD_B01(1); \
    if (S2) SB((T) + 2, 0); \
    BAR; P1; MM16_01(b0, b1); P0; BAR; \
    RD_B23(1); \
    if (S2) SA((T) + 2, 1); \
    VMW; \
    BAR; P1; MM16_23(b2, b3); P0; BAR; \
  } while (0)

  f32x4 acc[8][4];
#pragma unroll
  for (int i = 0; i < 8; ++i)
#pragma unroll
    for (int j = 0; j < 4; ++j) acc[i][j] = {0.f, 0.f, 0.f, 0.f};

  // prologue: units u(0,0..3), u(1,0..2) in queue order; VM6 retires tile 0 exactly.
  SA(0, 0); SB(0, 0); SA(0, 1); SB(0, 1); SA(1, 0); SB(1, 0); SA(1, 1);
  VM6;
  BAR;

  for (int T = 0; T < 62; ++T) { KTILE(T, 1, 1, VM6); }
  KTILE(62, 1, 0, VM0);     // stages only u(63,3); drain so tile 63 fully landed
  KTILE(63, 0, 0, VMNOP);

  // epilogue: C = acc + bias   (C/D map: col = l&15, row = (l>>4)*4 + reg)
  const int crow = m0 + (wid >> 2) * 128 + ((l >> 4) << 2);
  const int ccol = n0 + (wid & 3) * 64 + (l & 15);
#pragma unroll
  for (int nf = 0; nf < 4; ++nf) {
    const float bv = Bias[ccol + nf * 16];
#pragma unroll
    for (int f = 0; f < 8; ++f)
#pragma unroll
      for (int rg = 0; rg < 4; ++rg)
        Out[(size_t)(crow + f * 16 + rg) * OUT_F + ccol + nf * 16] = acc[f][nf][rg] + bv;
  }
}

// ---------------- fallback: fused kernel (if ws too small / shape off) ----------------
__global__ __launch_bounds__(256, 2) void nf4_gemm_fused(
    const float* __restrict__ X, const int* __restrict__ Wp,
    const float* __restrict__ Amax, const float* __restrict__ Bias,
    float* __restrict__ Out, int M) {
  __shared__ unsigned short As[128 * 64];
  __shared__ unsigned short Bs[128 * 64];
  __shared__ float lutS[16];

  const int t = threadIdx.x;
  const int l = t & 63;
  const int wid = t >> 6;

  if (t < 16) {
    const float lut[16] = {-1.0f, -0.6961928009986877f, -0.5250730514526367f,
        -0.39491719007492065f, -0.28444138169288635f, -0.18477343022823334f,
        -0.08820830285549164f, 0.0f, 0.07107656449079514f, 0.14263366162776947f,
        0.22430233657360077f, 0.3203405737876892f, 0.4407068192958832f,
        0.5905631184577942f, 0.796090841293335f, 1.0f};
    lutS[t] = lut[t];
  }

  const int ntile = OUT_F / 128;
  const int m0 = (blockIdx.x / ntile) * 128;
  const int n0 = (blockIdx.x % ntile) * 128;

  const int ar = t >> 4;
  const int ac4 = t & 15;
  const int br = t >> 3;
  const int bg = t & 7;
  const int wm = (wid >> 1) * 64;
  const int wn = (wid & 1) * 64;

  f32x4 acc[4][4];
#pragma unroll
  for (int i = 0; i < 4; ++i)
#pragma unroll
    for (int j = 0; j < 4; ++j) acc[i][j] = {0.f, 0.f, 0.f, 0.f};

  __syncthreads();

  for (int k0 = 0; k0 < IN_F; k0 += 64) {
#pragma unroll
    for (int p = 0; p < 8; ++p) {
      const int r = p * 16 + ar;
      const float4 v = *reinterpret_cast<const float4*>(
          X + (size_t)(m0 + r) * IN_F + k0 + ac4 * 4);
      us4 h;
      h[0] = f2bf(v.x); h[1] = f2bf(v.y); h[2] = f2bf(v.z); h[3] = f2bf(v.w);
      const int byte = r * 128 + ((ac4 * 8) ^ ((r & 7) << 4));
      *reinterpret_cast<us4*>(reinterpret_cast<char*>(As) + byte) = h;
    }
#pragma unroll
    for (int p = 0; p < 4; ++p) {
      const int r = p * 32 + br;
      const float amv = Amax[(size_t)(n0 + r) * (IN_F / 64) + (k0 >> 6)];
      const int4 pk = *reinterpret_cast<const int4*>(
          Wp + (size_t)(n0 + r) * (IN_F / 2) + (k0 >> 1) + bg * 4);
      us8 h;
      {
        int c;
        c = pk.x & 255; h[0] = f2bf(lutS[c & 15] * amv); h[1] = f2bf(lutS[c >> 4] * amv);
        c = pk.y & 255; h[2] = f2bf(lutS[c & 15] * amv); h[3] = f2bf(lutS[c >> 4] * amv);
        c = pk.z & 255; h[4] = f2bf(lutS[c & 15] * amv); h[5] = f2bf(lutS[c >> 4] * amv);
        c = pk.w & 255; h[6] = f2bf(lutS[c & 15] * amv); h[7] = f2bf(lutS[c >> 4] * amv);
      }
      const int byte = r * 128 + ((bg * 16) ^ ((r & 7) << 4));
      *reinterpret_cast<us8*>(reinterpret_cast<char*>(Bs) + byte) = h;
    }
    __syncthreads();

#pragma unroll
    for (int kk = 0; kk < 64; kk += 32) {
      bf16x8 af[4], bfv[4];
      const int kb = (kk + ((l >> 4) << 3)) * 2;
#pragma unroll
      for (int i = 0; i < 4; ++i) {
        const int row = wm + i * 16 + (l & 15);
        af[i] = *reinterpret_cast<const bf16x8*>(
            reinterpret_cast<const char*>(As) + row * 128 + (kb ^ ((row & 7) << 4)));
      }
#pragma unroll
      for (int j = 0; j < 4; ++j) {
        const int row = wn + j * 16 + (l & 15);
        bfv[j] = *reinterpret_cast<const bf16x8*>(
            reinterpret_cast<const char*>(Bs) + row * 128 + (kb ^ ((row & 7) << 4)));
      }
#pragma unroll
      for (int i = 0; i < 4; ++i)
#pragma unroll
        for (int j = 0; j < 4; ++j)
          acc[i][j] = __builtin_amdgcn_mfma_f32_16x16x32_bf16(af[i], bfv[j], acc[i][j], 0, 0, 0);
    }
    __syncthreads();
  }

  const int crow0 = m0 + wm + ((l >> 4) << 2);
  const int ccol0 = n0 + wn + (l & 15);
#pragma unroll
  for (int j = 0; j < 4; ++j) {
    const float bv = Bias[ccol0 + j * 16];
#pragma unroll
    for (int i = 0; i < 4; ++i)
#pragma unroll
      for (int rg = 0; rg < 4; ++rg)
        Out[(size_t)(crow0 + i * 16 + rg) * OUT_F + ccol0 + j * 16] = acc[i][j][rg] + bv;
  }
}

extern "C" void kernel_launch(void* const* d_in, const int* in_sizes, int n_in,
                              void* d_out, int out_size, void* d_ws, size_t ws_size,
                              hipStream_t stream) {
  const float* X = (const float*)d_in[0];
  const int* Wp = (const int*)d_in[1];
  const float* Amax = (const float*)d_in[2];
  const float* Bias = (const float*)d_in[3];
  float* Out = (float*)d_out;

  const int M = in_sizes[0] / IN_F;                       // 8192
  const size_t needX = (size_t)M * IN_F * 2;
  const size_t needW = (size_t)OUT_F * IN_F * 2;
  const int grid256 = (M / 256) * (OUT_F / 256);          // 32*43 = 1376

  if (ws_size >= needX + needW && (M % 256) == 0 && (grid256 & 7) == 0) {
    unsigned short* Xb = (unsigned short*)d_ws;
    unsigned short* Wb = Xb + (size_t)M * IN_F;
    (void)hipFuncSetAttribute(reinterpret_cast<const void*>(gemm256),
                              hipFuncAttributeMaxDynamicSharedMemorySize, 131072);
    cvt_x<<<2048, 256, 0, stream>>>(X, Xb, M * (IN_F / 8));
    dequant_w<<<2048, 256, 0, stream>>>(Wp, Amax, Wb, OUT_F * (IN_F / 8));
    gemm256<<<grid256, 512, 131072, stream>>>(Xb, Wb, Bias, Out, M);
  } else {
    const int grid = (M / 128) * (OUT_F / 128);
    nf4_gemm_fused<<<grid, 256, 0, stream>>>(X, Wp, Amax, Bias, Out, M);
  }
}

// Round 8
// 794.255 us; speedup vs baseline: 1.1494x; 1.1494x over previous
//
#include <hip/hip_runtime.h>

#define IN_F 4096
#define OUT_F 11008

typedef __attribute__((ext_vector_type(8))) short bf16x8;   // 8 bf16 (4 VGPR) MFMA operand
typedef __attribute__((ext_vector_type(4))) float f32x4;
typedef __attribute__((ext_vector_type(4))) unsigned short us4;
typedef __attribute__((ext_vector_type(8))) unsigned short us8;

__device__ __forceinline__ unsigned short f2bf(float f) {
  unsigned int u = __float_as_uint(f);
  u += 0x7FFFu + ((u >> 16) & 1u);   // RNE
  return (unsigned short)(u >> 16);
}

// ---------------- prepass 1: X fp32 -> bf16 ----------------
__global__ __launch_bounds__(256) void cvt_x(const float* __restrict__ X,
                                             unsigned short* __restrict__ Xb, int n8) {
  for (int i = blockIdx.x * blockDim.x + threadIdx.x; i < n8;
       i += gridDim.x * blockDim.x) {
    const float4 a = reinterpret_cast<const float4*>(X)[2 * i];
    const float4 b = reinterpret_cast<const float4*>(X)[2 * i + 1];
    us8 h;
    h[0] = f2bf(a.x); h[1] = f2bf(a.y); h[2] = f2bf(a.z); h[3] = f2bf(a.w);
    h[4] = f2bf(b.x); h[5] = f2bf(b.y); h[6] = f2bf(b.z); h[7] = f2bf(b.w);
    reinterpret_cast<us8*>(Xb)[i] = h;
  }
}

// ---------------- prepass 2: W nf4 packed -> bf16 (dequant once) ----------------
__global__ __launch_bounds__(256) void dequant_w(const int* __restrict__ Wp,
                                                 const float* __restrict__ Amax,
                                                 unsigned short* __restrict__ Wb, int n4) {
  __shared__ float lutS[16];
  if (threadIdx.x < 16) {
    const float lut[16] = {-1.0f, -0.6961928009986877f, -0.5250730514526367f,
        -0.39491719007492065f, -0.28444138169288635f, -0.18477343022823334f,
        -0.08820830285549164f, 0.0f, 0.07107656449079514f, 0.14263366162776947f,
        0.22430233657360077f, 0.3203405737876892f, 0.4407068192958832f,
        0.5905631184577942f, 0.796090841293335f, 1.0f};
    lutS[threadIdx.x] = lut[threadIdx.x];
  }
  __syncthreads();
  for (int i = blockIdx.x * blockDim.x + threadIdx.x; i < n4;
       i += gridDim.x * blockDim.x) {
    const int j = i * 4;
    const int row = j >> 11;
    const int coli = j & 2047;
    const float am = Amax[row * (IN_F / 64) + (coli >> 5)];
    const int4 pk = reinterpret_cast<const int4*>(Wp)[i];
    us8 h; int c;
    c = pk.x & 255; h[0] = f2bf(lutS[c & 15] * am); h[1] = f2bf(lutS[c >> 4] * am);
    c = pk.y & 255; h[2] = f2bf(lutS[c & 15] * am); h[3] = f2bf(lutS[c >> 4] * am);
    c = pk.z & 255; h[4] = f2bf(lutS[c & 15] * am); h[5] = f2bf(lutS[c >> 4] * am);
    c = pk.w & 255; h[6] = f2bf(lutS[c & 15] * am); h[7] = f2bf(lutS[c >> 4] * am);
    reinterpret_cast<us8*>(Wb)[i] = h;
  }
}

// ---------------- main GEMM: 256x256, BK=64, dbuf-2, 4 phases/K-tile ----------------
#define MF(a, b, c) __builtin_amdgcn_mfma_f32_16x16x32_bf16(a, b, c, 0, 0, 0)
#define GLDS(src, dst) __builtin_amdgcn_global_load_lds( \
    (const __attribute__((address_space(1))) void*)(src), \
    (__attribute__((address_space(3))) void*)(dst), 16, 0, 0)
#define FENCE asm volatile("" ::: "memory")
#define BAR do { FENCE; __builtin_amdgcn_s_barrier(); FENCE; } while (0)
#define VM6 asm volatile("s_waitcnt vmcnt(6)" ::: "memory")
#define VM0 asm volatile("s_waitcnt vmcnt(0)" ::: "memory")
#define VMNOP do {} while (0)
#define P1 __builtin_amdgcn_s_setprio(1)
#define P0 __builtin_amdgcn_s_setprio(0)

__global__ __launch_bounds__(512, 2) void gemm256(
    const unsigned short* __restrict__ A,   // (M, K) bf16
    const unsigned short* __restrict__ B,   // (N, K) bf16
    const float* __restrict__ Bias, float* __restrict__ Out, int M) {
  extern __shared__ unsigned short sm[];    // 128 KiB = 2 bufs x {A kh0,A kh1,B kh0,B kh1} x 16 KiB
  char* const smc = (char*)sm;

  const int tid = threadIdx.x;
  const int l = tid & 63;
  const int wid = tid >> 6;

  const int Mb = M / 256;                   // 32
  const int Nb = OUT_F / 256;               // 43

  // Supertile order: 16 m-rows x all Nb per supertile (A window 32MB L3-resident),
  // XCD-chunked inside (bps = 16*Nb always %8==0; needs Mb%16==0 -> launcher guard).
  const int bps = 16 * Nb;                  // 688 blocks per supertile
  const int pxc = bps >> 3;                 // 86 per XCD
  const int i6 = (int)blockIdx.x % bps;
  const int sup = (int)blockIdx.x / bps;
  const int k = (i6 & 7) * pxc + (i6 >> 3);
  const int m0 = (sup * 16 + (k & 15)) * 256;
  const int n0 = (k >> 4) * 256;

  // ---- read-side lane constant: logical (r,c) stored at chunk c ^ ((r>>1)&3) ----
  // (64B rows: 8-lane group rows r..r+7 -> units (4r + c^s(r)) mod 8 all distinct)
  const int lv = (l & 15) * 64 + (((l >> 4) ^ ((l >> 1) & 3)) * 16);   // bytes
  const int aLane = (wid >> 2) * 8192 + lv;            // + m*1024 per A frag
  const int bLane = 32768 + (wid & 3) * 4096 + lv;     // + j*1024 per B frag

  // ---- stage-side lane constants (inverse-swizzled global source, linear LDS dest) ----
  const int rq = tid >> 2;                                   // dest row (tid*16B linear)
  const int cs = (tid & 3) ^ ((tid >> 3) & 3);               // content k-chunk = p ^ s(r)
  const unsigned short* gAs = A + (size_t)(m0 + rq) * IN_F + cs * 8;
  const unsigned short* gBs = B + (size_t)(n0 + rq) * IN_F + cs * 8;

  // unit = 16 KiB (256 rows x 32 k): 2 x global_load_lds per thread (+128 rows)
#define SA(t, kh) do { \
    unsigned short* d_ = sm + (size_t)((((t) & 1) * 4096) + (kh) * 1024 + wid * 64) * 8; \
    const unsigned short* s_ = gAs + (size_t)(t) * 64 + (kh) * 32; \
    GLDS(s_, d_); GLDS(s_ + 524288, d_ + 4096); } while (0)
#define SB(t, kh) do { \
    unsigned short* d_ = sm + (size_t)((((t) & 1) * 4096) + 2048 + (kh) * 1024 + wid * 64) * 8; \
    const unsigned short* s_ = gBs + (size_t)(t) * 64 + (kh) * 32; \
    GLDS(s_, d_); GLDS(s_ + 524288, d_ + 4096); } while (0)

#define RD_A(kh) do { const char* p_ = LAb + (kh) * 16384; \
    a0 = *(const bf16x8*)(p_);        a1 = *(const bf16x8*)(p_ + 1024); \
    a2 = *(const bf16x8*)(p_ + 2048); a3 = *(const bf16x8*)(p_ + 3072); \
    a4 = *(const bf16x8*)(p_ + 4096); a5 = *(const bf16x8*)(p_ + 5120); \
    a6 = *(const bf16x8*)(p_ + 6144); a7 = *(const bf16x8*)(p_ + 7168); } while (0)
#define RD_B01(kh) do { const char* p_ = LBb + (kh) * 16384; \
    b0 = *(const bf16x8*)(p_); b1 = *(const bf16x8*)(p_ + 1024); } while (0)
#define RD_B23(kh) do { const char* p_ = LBb + (kh) * 16384 + 2048; \
    b2 = *(const bf16x8*)(p_); b3 = *(const bf16x8*)(p_ + 1024); } while (0)

#define MM16_01(B0, B1) do { \
    acc[0][0]=MF(a0,B0,acc[0][0]); acc[0][1]=MF(a0,B1,acc[0][1]); \
    acc[1][0]=MF(a1,B0,acc[1][0]); acc[1][1]=MF(a1,B1,acc[1][1]); \
    acc[2][0]=MF(a2,B0,acc[2][0]); acc[2][1]=MF(a2,B1,acc[2][1]); \
    acc[3][0]=MF(a3,B0,acc[3][0]); acc[3][1]=MF(a3,B1,acc[3][1]); \
    acc[4][0]=MF(a4,B0,acc[4][0]); acc[4][1]=MF(a4,B1,acc[4][1]); \
    acc[5][0]=MF(a5,B0,acc[5][0]); acc[5][1]=MF(a5,B1,acc[5][1]); \
    acc[6][0]=MF(a6,B0,acc[6][0]); acc[6][1]=MF(a6,B1,acc[6][1]); \
    acc[7][0]=MF(a7,B0,acc[7][0]); acc[7][1]=MF(a7,B1,acc[7][1]); } while (0)
#define MM16_23(B2, B3) do { \
    acc[0][2]=MF(a0,B2,acc[0][2]); acc[0][3]=MF(a0,B3,acc[0][3]); \
    acc[1][2]=MF(a1,B2,acc[1][2]); acc[1][3]=MF(a1,B3,acc[1][3]); \
    acc[2][2]=MF(a2,B2,acc[2][2]); acc[2][3]=MF(a2,B3,acc[2][3]); \
    acc[3][2]=MF(a3,B2,acc[3][2]); acc[3][3]=MF(a3,B3,acc[3][3]); \
    acc[4][2]=MF(a4,B2,acc[4][2]); acc[4][3]=MF(a4,B3,acc[4][3]); \
    acc[5][2]=MF(a5,B2,acc[5][2]); acc[5][3]=MF(a5,B3,acc[5][3]); \
    acc[6][2]=MF(a6,B2,acc[6][2]); acc[6][3]=MF(a6,B3,acc[6][3]); \
    acc[7][2]=MF(a7,B2,acc[7][2]); acc[7][3]=MF(a7,B3,acc[7][3]); } while (0)

  // KTILE(T): 4 phases; stage cadence p0:u(T+1,3) p1:u(T+2,0) p2:u(T+2,1) p3:u(T+2,2);
  // single VM6 at p3 (pre-BAR; next tile's reads post-BAR => all waves' loads landed).
  // WAR: each unit staged in the phase AFTER its region's last read (barrier-ordered).
#define KTILE(T, S1, S2, VMW) do { \
    const char* LAb = smc + (((T) & 1) << 16) + aLane; \
    const char* LBb = smc + (((T) & 1) << 16) + bLane; \
    bf16x8 a0, a1, a2, a3, a4, a5, a6, a7, b0, b1, b2, b3; \
    RD_A(0); RD_B01(0); \
    if (S1) SB((T) + 1, 1); \
    BAR; P1; MM16_01(b0, b1); P0; BAR; \
    RD_B23(0); \
    if (S2) SA((T) + 2, 0); \
    BAR; P1; MM16_23(b2, b3); P0; BAR; \
    RD_A(1); RD_B01(1); \
    if (S2) SB((T) + 2, 0); \
    BAR; P1; MM16_01(b0, b1); P0; BAR; \
    RD_B23(1); \
    if (S2) SA((T) + 2, 1); \
    VMW; \
    BAR; P1; MM16_23(b2, b3); P0; BAR; \
  } while (0)

  f32x4 acc[8][4];
#pragma unroll
  for (int i = 0; i < 8; ++i)
#pragma unroll
    for (int j = 0; j < 4; ++j) acc[i][j] = {0.f, 0.f, 0.f, 0.f};

  // prologue: units u(0,0..3), u(1,0..2) in queue order; VM6 retires tile 0 exactly.
  SA(0, 0); SB(0, 0); SA(0, 1); SB(0, 1); SA(1, 0); SB(1, 0); SA(1, 1);
  VM6;
  BAR;

  for (int T = 0; T < 62; ++T) { KTILE(T, 1, 1, VM6); }
  KTILE(62, 1, 0, VM0);     // stages only u(63,3); drain so tile 63 fully landed
  KTILE(63, 0, 0, VMNOP);

  // epilogue: C = acc + bias   (C/D map: col = l&15, row = (l>>4)*4 + reg)
  const int crow = m0 + (wid >> 2) * 128 + ((l >> 4) << 2);
  const int ccol = n0 + (wid & 3) * 64 + (l & 15);
#pragma unroll
  for (int nf = 0; nf < 4; ++nf) {
    const float bv = Bias[ccol + nf * 16];
#pragma unroll
    for (int f = 0; f < 8; ++f)
#pragma unroll
      for (int rg = 0; rg < 4; ++rg)
        Out[(size_t)(crow + f * 16 + rg) * OUT_F + ccol + nf * 16] = acc[f][nf][rg] + bv;
  }
}

// ---------------- fallback: fused kernel (if ws too small / shape off) ----------------
__global__ __launch_bounds__(256, 2) void nf4_gemm_fused(
    const float* __restrict__ X, const int* __restrict__ Wp,
    const float* __restrict__ Amax, const float* __restrict__ Bias,
    float* __restrict__ Out, int M) {
  __shared__ unsigned short As[128 * 64];
  __shared__ unsigned short Bs[128 * 64];
  __shared__ float lutS[16];

  const int t = threadIdx.x;
  const int l = t & 63;
  const int wid = t >> 6;

  if (t < 16) {
    const float lut[16] = {-1.0f, -0.6961928009986877f, -0.5250730514526367f,
        -0.39491719007492065f, -0.28444138169288635f, -0.18477343022823334f,
        -0.08820830285549164f, 0.0f, 0.07107656449079514f, 0.14263366162776947f,
        0.22430233657360077f, 0.3203405737876892f, 0.4407068192958832f,
        0.5905631184577942f, 0.796090841293335f, 1.0f};
    lutS[t] = lut[t];
  }

  const int ntile = OUT_F / 128;
  const int m0 = (blockIdx.x / ntile) * 128;
  const int n0 = (blockIdx.x % ntile) * 128;

  const int ar = t >> 4;
  const int ac4 = t & 15;
  const int br = t >> 3;
  const int bg = t & 7;
  const int wm = (wid >> 1) * 64;
  const int wn = (wid & 1) * 64;

  f32x4 acc[4][4];
#pragma unroll
  for (int i = 0; i < 4; ++i)
#pragma unroll
    for (int j = 0; j < 4; ++j) acc[i][j] = {0.f, 0.f, 0.f, 0.f};

  __syncthreads();

  for (int k0 = 0; k0 < IN_F; k0 += 64) {
#pragma unroll
    for (int p = 0; p < 8; ++p) {
      const int r = p * 16 + ar;
      const float4 v = *reinterpret_cast<const float4*>(
          X + (size_t)(m0 + r) * IN_F + k0 + ac4 * 4);
      us4 h;
      h[0] = f2bf(v.x); h[1] = f2bf(v.y); h[2] = f2bf(v.z); h[3] = f2bf(v.w);
      const int byte = r * 128 + ((ac4 * 8) ^ ((r & 7) << 4));
      *reinterpret_cast<us4*>(reinterpret_cast<char*>(As) + byte) = h;
    }
#pragma unroll
    for (int p = 0; p < 4; ++p) {
      const int r = p * 32 + br;
      const float amv = Amax[(size_t)(n0 + r) * (IN_F / 64) + (k0 >> 6)];
      const int4 pk = *reinterpret_cast<const int4*>(
          Wp + (size_t)(n0 + r) * (IN_F / 2) + (k0 >> 1) + bg * 4);
      us8 h;
      {
        int c;
        c = pk.x & 255; h[0] = f2bf(lutS[c & 15] * amv); h[1] = f2bf(lutS[c >> 4] * amv);
        c = pk.y & 255; h[2] = f2bf(lutS[c & 15] * amv); h[3] = f2bf(lutS[c >> 4] * amv);
        c = pk.z & 255; h[4] = f2bf(lutS[c & 15] * amv); h[5] = f2bf(lutS[c >> 4] * amv);
        c = pk.w & 255; h[6] = f2bf(lutS[c & 15] * amv); h[7] = f2bf(lutS[c >> 4] * amv);
      }
      const int byte = r * 128 + ((bg * 16) ^ ((r & 7) << 4));
      *reinterpret_cast<us8*>(reinterpret_cast<char*>(Bs) + byte) = h;
    }
    __syncthreads();

#pragma unroll
    for (int kk = 0; kk < 64; kk += 32) {
      bf16x8 af[4], bfv[4];
      const int kb = (kk + ((l >> 4) << 3)) * 2;
#pragma unroll
      for (int i = 0; i < 4; ++i) {
        const int row = wm + i * 16 + (l & 15);
        af[i] = *reinterpret_cast<const bf16x8*>(
            reinterpret_cast<const char*>(As) + row * 128 + (kb ^ ((row & 7) << 4)));
      }
#pragma unroll
      for (int j = 0; j < 4; ++j) {
        const int row = wn + j * 16 + (l & 15);
        bfv[j] = *reinterpret_cast<const bf16x8*>(
            reinterpret_cast<const char*>(Bs) + row * 128 + (kb ^ ((row & 7) << 4)));
      }
#pragma unroll
      for (int i = 0; i < 4; ++i)
#pragma unroll
        for (int j = 0; j < 4; ++j)
          acc[i][j] = __builtin_amdgcn_mfma_f32_16x16x32_bf16(af[i], bfv[j], acc[i][j], 0, 0, 0);
    }
    __syncthreads();
  }

  const int crow0 = m0 + wm + ((l >> 4) << 2);
  const int ccol0 = n0 + wn + (l & 15);
#pragma unroll
  for (int j = 0; j < 4; ++j) {
    const float bv = Bias[ccol0 + j * 16];
#pragma unroll
    for (int i = 0; i < 4; ++i)
#pragma unroll
      for (int rg = 0; rg < 4; ++rg)
        Out[(size_t)(crow0 + i * 16 + rg) * OUT_F + ccol0 + j * 16] = acc[i][j][rg] + bv;
  }
}

extern "C" void kernel_launch(void* const* d_in, const int* in_sizes, int n_in,
                              void* d_out, int out_size, void* d_ws, size_t ws_size,
                              hipStream_t stream) {
  const float* X = (const float*)d_in[0];
  const int* Wp = (const int*)d_in[1];
  const float* Amax = (const float*)d_in[2];
  const float* Bias = (const float*)d_in[3];
  float* Out = (float*)d_out;

  const int M = in_sizes[0] / IN_F;                       // 8192
  const size_t needX = (size_t)M * IN_F * 2;
  const size_t needW = (size_t)OUT_F * IN_F * 2;
  const int grid256 = (M / 256) * (OUT_F / 256);          // 32*43 = 1376

  if (ws_size >= needX + needW && (M % 4096) == 0) {      // Mb%16==0 for supertile map
    unsigned short* Xb = (unsigned short*)d_ws;
    unsigned short* Wb = Xb + (size_t)M * IN_F;
    (void)hipFuncSetAttribute(reinterpret_cast<const void*>(gemm256),
                              hipFuncAttributeMaxDynamicSharedMemorySize, 131072);
    cvt_x<<<2048, 256, 0, stream>>>(X, Xb, M * (IN_F / 8));
    dequant_w<<<2048, 256, 0, stream>>>(Wp, Amax, Wb, OUT_F * (IN_F / 8));
    gemm256<<<grid256, 512, 131072, stream>>>(Xb, Wb, Bias, Out, M);
  } else {
    const int grid = (M / 128) * (OUT_F / 128);
    nf4_gemm_fused<<<grid, 256, 0, stream>>>(X, Wp, Amax, Bias, Out, M);
  }
}